// Round 13
// baseline (818.148 us; speedup 1.0000x reference)
//
#include <hip/hip_runtime.h>

typedef unsigned short u16;
typedef unsigned int u32;
typedef __attribute__((ext_vector_type(4))) float f32x4;
typedef __attribute__((ext_vector_type(8))) __bf16 bf16x8;
typedef __attribute__((ext_vector_type(8))) unsigned short u16x8;

#if defined(__has_builtin)
#if __has_builtin(__builtin_amdgcn_global_load_lds)
#define HAS_GLL 1
#endif
#endif

__device__ __forceinline__ u16 f2bf(float f) {
    u32 u = __builtin_bit_cast(u32, f);
    u += 0x7fffu + ((u >> 16) & 1u);
    return (u16)(u >> 16);
}
__device__ __forceinline__ float bf2f(u16 x) {
    return __builtin_bit_cast(float, (u32)x << 16);
}

// counted-vmcnt barrier: wait until <= N vector-memory ops outstanding, then barrier.
template <int N> __device__ __forceinline__ void wbar() {
#ifdef HAS_GLL
    if constexpr (N == 0)
        asm volatile("s_waitcnt vmcnt(0)\n\ts_barrier" ::: "memory");
    else if constexpr (N == 2)
        asm volatile("s_waitcnt vmcnt(2)\n\ts_barrier" ::: "memory");
    else
        asm volatile("s_waitcnt vmcnt(4)\n\ts_barrier" ::: "memory");
#else
    __syncthreads();
#endif
}

// full drain barrier (vm + lgkm)
__device__ __forceinline__ void fbar() {
#ifdef HAS_GLL
    asm volatile("s_waitcnt vmcnt(0) lgkmcnt(0)\n\ts_barrier" ::: "memory");
#else
    __syncthreads();
#endif
}

// lgkm-drain barrier (LDS writes visible; no VMEM drain)
__device__ __forceinline__ void lbar() {
#ifdef HAS_GLL
    asm volatile("s_waitcnt lgkmcnt(0)\n\ts_barrier" ::: "memory");
#else
    __syncthreads();
#endif
}

// ---------------- utility kernels ----------------
__global__ __launch_bounds__(256) void zero_kernel(float* __restrict__ p, int n) {
    int i = blockIdx.x * 256 + threadIdx.x;
    if (i < n) p[i] = 0.f;
}

__global__ __launch_bounds__(256) void cvt_bf16_kernel(const float4* __restrict__ in,
                                                       ushort4* __restrict__ out, int n4) {
    int i = blockIdx.x * 256 + threadIdx.x;
    if (i < n4) {
        float4 v = in[i];
        ushort4 o;
        o.x = f2bf(v.x); o.y = f2bf(v.y); o.z = f2bf(v.z); o.w = f2bf(v.w);
        out[i] = o;
    }
}

// transpose + convert: W [B][K][N] f32 -> Wt [B][N][K] bf16
__global__ __launch_bounds__(256) void transcvt_kernel(const float* __restrict__ W,
                                                       u16* __restrict__ Wt, int K, int N) {
    __shared__ u16 t[32][33];
    int b = blockIdx.z;
    const float* Wb = W + (size_t)b * K * N;
    u16* Wtb = Wt + (size_t)b * K * N;
    int n0 = blockIdx.x * 32, k0 = blockIdx.y * 32;
    int tx = threadIdx.x, ty = threadIdx.y;
#pragma unroll
    for (int j = 0; j < 4; ++j)
        t[ty + j * 8][tx] = f2bf(Wb[(size_t)(k0 + ty + j * 8) * N + n0 + tx]);
    __syncthreads();
#pragma unroll
    for (int j = 0; j < 4; ++j)
        Wtb[(size_t)(n0 + ty + j * 8) * K + k0 + tx] = t[tx][ty + j * 8];
}

// ---------------- scale rows of [R][C] bf16 by rd[(r>>lg)*C + c]: mul ? * : / ----------------
__global__ __launch_bounds__(256) void scale_rows_kernel(const u16* __restrict__ in,
                                                         u16* __restrict__ out,
                                                         const float* __restrict__ rd,
                                                         int C, int lgdk, int mul) {
    int i = (blockIdx.x * 256 + threadIdx.x) * 8;
    int r = i / C, c = i % C;
    const float* rdp = rd + ((size_t)(r >> lgdk)) * C + c;
    u16x8 x = *reinterpret_cast<const u16x8*>(in + i);
    u16x8 o;
#pragma unroll
    for (int j = 0; j < 8; ++j)
        o[j] = f2bf(mul ? bf2f(x[j]) * rdp[j] : bf2f(x[j]) / rdp[j]);
    *reinterpret_cast<u16x8*>(out + i) = o;
}

// ---------------- fused stage-1 attention v2 (A in regs, B/V dbuf, counted vmcnt) ----------------
// NORM=1: out = elu((expS @ V^T)/rowsum), writes rsinv[h][row].
// NORM=0: V pre-scaled by rsinv (per key-column); P = raw expS; out = elu(P @ V^T).
struct FGrp { const u16* A; const u16* B; const u16* V; float* O; float* rs; int M; int NK; int mask; };
struct FCfg { FGrp g[3]; };

template <int NORM>
__global__ __launch_bounds__(256) void fused_attn1_kernel(FCfg cfg, float scale) {
    __shared__ __align__(16) u16 Bbuf[2][4 * 2048];    // 32KB double-buffered key tiles
    __shared__ __align__(16) u16 Vbuf[2][2 * 4096];    // 32KB double-buffered V tiles
    __shared__ __align__(16) u16 Pbuf[2 * 2048];       // 8KB
    __shared__ float rsum_lds[64][2];
    const int gi = blockIdx.z >> 2, h = blockIdx.z & 3;
    FGrp G = (gi == 0) ? cfg.g[0] : (gi == 1) ? cfg.g[1] : cfg.g[2];
    const int row0 = blockIdx.x * 64;
    if (row0 >= G.M) return;
    const u16* Ap = G.A + h * 128;                     // lda 512
    const u16* Bp = G.B + h * 128;                     // ldb 512
    const u16* Vp = G.V + (size_t)h * 128 * G.NK;      // ldv NK
    float* Op = G.O + h * 128;                         // ldo 512
    const int ldv = G.NK;
    const int tid = threadIdx.x, lane = tid & 63, wid = tid >> 6;
    const int swr = (wid >> 1) * 32, swc = (wid & 1) * 32;
    const int pwr = swr, pwc = (wid & 1) * 64;

    auto gld = [&](const u16* src, u16* dst) {
#ifdef HAS_GLL
        __builtin_amdgcn_global_load_lds(
            (const __attribute__((address_space(1))) void*)src,
            (__attribute__((address_space(3))) void*)dst, 16, 0, 0);
#else
        *reinterpret_cast<uint4*>(dst) = *reinterpret_cast<const uint4*>(src);
#endif
    };
    auto stageB = [&](int t, int buf) {
#pragma unroll
        for (int it = 0; it < 4; ++it) {
            int c = tid + it * 256;
            int kb = c >> 8, cc = c & 255;
            int r = cc >> 2, lch = (cc & 3) ^ ((r >> 1) & 3);
            gld(Bp + (size_t)(t * 64 + r) * 512 + kb * 32 + lch * 8, &Bbuf[buf][kb * 2048 + cc * 8]);
        }
    };
    auto stageV = [&](int t, int buf) {
#pragma unroll
        for (int it = 0; it < 4; ++it) {
            int c = tid + it * 256;
            int kb = c >> 9, cc = c & 511;
            int r = cc >> 2, lch = (cc & 3) ^ ((r >> 1) & 3);
            gld(Vp + (size_t)r * ldv + t * 64 + kb * 32 + lch * 8, &Vbuf[buf][kb * 4096 + cc * 8]);
        }
    };

    // ---- A tile directly into registers (layout = de-swizzled staging layout) ----
    bf16x8 areg[2][4];
#pragma unroll
    for (int m = 0; m < 2; ++m) {
        int rr = swr + m * 16 + (lane & 15);
#pragma unroll
        for (int kk = 0; kk < 4; ++kk)
            areg[m][kk] = *reinterpret_cast<const bf16x8*>(
                Ap + (size_t)(row0 + rr) * 512 + kk * 32 + (lane >> 4) * 8);
    }
    // prologue: stage tiles 0 and 1 fully, single full drain
    stageB(0, 0);
    stageV(0, 0);
    stageB(1, 1);
    stageV(1, 1);
    fbar();

    f32x4 accp[2][4] = {};
    float rsum[2][4] = {};
    const int nt = G.NK >> 6;
    for (int t = 0; t < nt; ++t) {
        const int cur = t & 1;
        // ---- S phase: A-regs x Bbuf[cur] ----
        f32x4 accs[2][2] = {};
#pragma unroll
        for (int kk = 0; kk < 4; ++kk) {
            bf16x8 bf[2];
#pragma unroll
            for (int n = 0; n < 2; ++n) {
                int rr = swc + n * 16 + (lane & 15);
                int p = (lane >> 4) ^ ((rr >> 1) & 3);
                bf[n] = *reinterpret_cast<const bf16x8*>(&Bbuf[cur][kk * 2048 + rr * 32 + p * 8]);
            }
#pragma unroll
            for (int m = 0; m < 2; ++m)
#pragma unroll
                for (int n = 0; n < 2; ++n)
                    accs[m][n] = __builtin_amdgcn_mfma_f32_16x16x32_bf16(areg[m][kk], bf[n], accs[m][n], 0, 0, 0);
        }
        // ---- exp (+rowsum if NORM) + P write (staging layout, chunk-XOR) ----
#pragma unroll
        for (int m = 0; m < 2; ++m) {
#pragma unroll
            for (int n = 0; n < 2; ++n) {
#pragma unroll
                for (int j = 0; j < 4; ++j) {
                    int prow = swr + m * 16 + ((lane >> 4) << 2) + j;
                    int pkey = swc + n * 16 + (lane & 15);
                    float v = __expf(accs[m][n][j] * scale);
                    if (G.mask && (row0 + prow == t * 64 + pkey)) v = 0.f;
                    if (NORM == 1) rsum[m][j] += v;
                    Pbuf[(pkey >> 5) * 2048 + prow * 32 +
                         ((((pkey >> 3) & 3) ^ ((prow >> 1) & 3)) << 3) + (pkey & 7)] = f2bf(v);
                }
            }
        }
        lbar();                                   // alpha: P visible; B[cur] reads retired
        if (t + 2 < nt) stageB(t + 2, cur);       // overwrite B[cur] (safe past alpha)
        // ---- PV phase ----
#pragma unroll
        for (int kk = 0; kk < 2; ++kk) {
            bf16x8 pf[2], vf[4];
#pragma unroll
            for (int m = 0; m < 2; ++m) {
                int rr = pwr + m * 16 + (lane & 15);
                int p = (lane >> 4) ^ ((rr >> 1) & 3);
                pf[m] = *reinterpret_cast<const bf16x8*>(&Pbuf[kk * 2048 + rr * 32 + p * 8]);
            }
#pragma unroll
            for (int n = 0; n < 4; ++n) {
                int dd = pwc + n * 16 + (lane & 15);
                int p = (lane >> 4) ^ ((dd >> 1) & 3);
                vf[n] = *reinterpret_cast<const bf16x8*>(&Vbuf[cur][kk * 4096 + dd * 32 + p * 8]);
            }
#pragma unroll
            for (int m = 0; m < 2; ++m)
#pragma unroll
                for (int n = 0; n < 4; ++n)
                    accp[m][n] = __builtin_amdgcn_mfma_f32_16x16x32_bf16(pf[m], vf[n], accp[m][n], 0, 0, 0);
        }
        // gamma: drain B(t+1),V(t+1) (keep B(t+2) flying); all PV reads retired
        if (t + 2 < nt)      wbar<4>();
        else if (t + 1 < nt) wbar<0>();
        if (t + 2 < nt) stageV(t + 2, cur);       // overwrite V[cur] (safe past gamma)
    }

    if (NORM == 1) {
        // ---- rowsum merge across the 2 key-slice waves ----
#pragma unroll
        for (int m = 0; m < 2; ++m)
#pragma unroll
            for (int j = 0; j < 4; ++j) {
                float s = rsum[m][j];
                s += __shfl_xor(s, 1); s += __shfl_xor(s, 2);
                s += __shfl_xor(s, 4); s += __shfl_xor(s, 8);
                rsum[m][j] = s;
            }
        if ((lane & 15) == 0) {
#pragma unroll
            for (int m = 0; m < 2; ++m)
#pragma unroll
                for (int j = 0; j < 4; ++j)
                    rsum_lds[swr + m * 16 + ((lane >> 4) << 2) + j][wid & 1] = rsum[m][j];
        }
        __syncthreads();
        if (tid < 64)
            G.rs[(size_t)h * G.M + row0 + tid] = 1.f / (rsum_lds[tid][0] + rsum_lds[tid][1]);
        // ---- scale + ELU + store ----
#pragma unroll
        for (int m = 0; m < 2; ++m) {
#pragma unroll
            for (int j = 0; j < 4; ++j) {
                int row = pwr + m * 16 + ((lane >> 4) << 2) + j;
                float rd = 1.f / (rsum_lds[row][0] + rsum_lds[row][1]);
#pragma unroll
                for (int n = 0; n < 4; ++n) {
                    float v = accp[m][n][j] * rd;
                    v = v > 0.f ? v : (__expf(v) - 1.f);
                    Op[(size_t)(row0 + row) * 512 + pwc + n * 16 + (lane & 15)] = v;
                }
            }
        }
    } else {
        // ---- normalization carried by pre-scaled V: ELU + store ----
#pragma unroll
        for (int m = 0; m < 2; ++m) {
#pragma unroll
            for (int j = 0; j < 4; ++j) {
                int row = pwr + m * 16 + ((lane >> 4) << 2) + j;
#pragma unroll
                for (int n = 0; n < 4; ++n) {
                    float v = accp[m][n][j];
                    v = v > 0.f ? v : (__expf(v) - 1.f);
                    Op[(size_t)(row0 + row) * 512 + pwc + n * 16 + (lane & 15)] = v;
                }
            }
        }
    }
}

// ---------------- GEMM: C = A (M,K) * B^T (N,K), row-major, 3-ring counted-vmcnt ----------------
enum { E_PROJ = 0, E_PROJT, E_EXP, E_EXPC, E_EXPT, E_EXPMT, E_PART };

template <int EPI, int BM>
__global__ __launch_bounds__(256) void gemm_nt(const u16* __restrict__ A, const u16* __restrict__ B,
                                               void* __restrict__ Cv, void* __restrict__ CvT,
                                               const float* __restrict__ bias, float* __restrict__ rs,
                                               int M, int N, int K, int lda, int ldb, int ldc, int ldcT,
                                               float scale, long sAz, long sBz, long sCz, long sCzT,
                                               long sBias, long sRs, int ZK, long sAz2, long sBz2) {
    constexpr bool HAS_BIAS = (EPI == E_PROJ || EPI == E_PROJT);
    constexpr bool DO_EXP = (EPI == E_EXP || EPI == E_EXPC || EPI == E_EXPT || EPI == E_EXPMT);
    constexpr bool DO_MASK = (EPI == E_EXPMT);
    constexpr int RSUM = (EPI == E_EXPC) ? 2 : (DO_EXP ? 1 : 0);
    constexpr bool STORE_N = (EPI != E_PROJT);
    constexpr bool STORE_T = (EPI == E_PROJT || EPI == E_EXPT || EPI == E_EXPMT);

    constexpr int MF = BM / 32;
    constexpr int ITERS = BM * 32 / (256 * 8);
    constexpr int LOADS = ITERS * 2;          // gload_lds per thread per stage()
    constexpr int SM_STAGE = 3 * BM * 64;
    constexpr int SM_REPACK = BM * BM;
    __shared__ __align__(16) u16 smem[SM_STAGE > SM_REPACK ? SM_STAGE : SM_REPACK];
    const int tid = threadIdx.x;
    const int lane = tid & 63;
    const int wid = tid >> 6;
    const int wr = (wid >> 1) * (BM / 2);
    const int wc = (wid & 1) * (BM / 2);
    const int row0 = blockIdx.x * BM;
    const int col0 = blockIdx.y * BM;
    const long zo = blockIdx.z;
    const long hz = zo / ZK;
    const long kz = zo - hz * ZK;
    const u16* Az = A + hz * sAz + kz * sAz2;
    const u16* Bz = B + hz * sBz + kz * sBz2;
    const float* biasz = bias ? bias + zo * sBias : nullptr;
    float* rsz = rs ? rs + zo * sRs : nullptr;
    f32x4 acc[MF][MF] = {};

    auto As = [&](int buf) { return smem + buf * (BM * 64); };
    auto Bs = [&](int buf) { return smem + buf * (BM * 64) + BM * 32; };

    auto stage = [&](int buf, int k0) {
#pragma unroll
        for (int i = 0; i < ITERS; ++i) {
            int c = tid + i * 256;
            int r = c >> 2;
            int lch = (c & 3) ^ ((r >> 1) & 3);
            const u16* sa = Az + (size_t)(row0 + r) * lda + k0 + lch * 8;
            const u16* sb = Bz + (size_t)(col0 + r) * ldb + k0 + lch * 8;
#ifdef HAS_GLL
            __builtin_amdgcn_global_load_lds(
                (const __attribute__((address_space(1))) void*)sa,
                (__attribute__((address_space(3))) void*)(&As(buf)[c * 8]), 16, 0, 0);
            __builtin_amdgcn_global_load_lds(
                (const __attribute__((address_space(1))) void*)sb,
                (__attribute__((address_space(3))) void*)(&Bs(buf)[c * 8]), 16, 0, 0);
#else
            *reinterpret_cast<uint4*>(&As(buf)[c * 8]) = *reinterpret_cast<const uint4*>(sa);
            *reinterpret_cast<uint4*>(&Bs(buf)[c * 8]) = *reinterpret_cast<const uint4*>(sb);
#endif
        }
    };

    stage(0, 0);
    stage(1, 32);
    wbar<LOADS>();

    const int nsteps = K >> 5;
    for (int t = 0; t < nsteps; ++t) {
        const int bufc = t % 3;
        const bool more2 = (t + 2 < nsteps);
        if (more2) stage((t + 2) % 3, (t + 2) << 5);
        bf16x8 af[MF], bv[MF];
#pragma unroll
        for (int m = 0; m < MF; ++m) {
            int rr = wr + m * 16 + (lane & 15);
            int p = (lane >> 4) ^ ((rr >> 1) & 3);
            af[m] = *reinterpret_cast<const bf16x8*>(&As(bufc)[rr * 32 + p * 8]);
        }
#pragma unroll
        for (int n = 0; n < MF; ++n) {
            int rr = wc + n * 16 + (lane & 15);
            int p = (lane >> 4) ^ ((rr >> 1) & 3);
            bv[n] = *reinterpret_cast<const bf16x8*>(&Bs(bufc)[rr * 32 + p * 8]);
        }
#pragma unroll
        for (int m = 0; m < MF; ++m)
#pragma unroll
            for (int n = 0; n < MF; ++n)
                acc[m][n] = __builtin_amdgcn_mfma_f32_16x16x32_bf16(af[m], bv[n], acc[m][n], 0, 0, 0);
        if (more2)                 wbar<LOADS>();
        else if (t + 1 < nsteps)   wbar<0>();
        else                       __syncthreads();
    }

    // ---- math pass ----
#pragma unroll
    for (int m = 0; m < MF; ++m) {
#pragma unroll
        for (int n = 0; n < MF; ++n) {
#pragma unroll
            for (int j = 0; j < 4; ++j) {
                float v = acc[m][n][j];
                if (HAS_BIAS) v += biasz[col0 + wc + n * 16 + (lane & 15)];
                if (DO_EXP) {
                    v = __expf(v * scale);
                    if (DO_MASK &&
                        row0 + wr + m * 16 + ((lane >> 4) << 2) + j ==
                        col0 + wc + n * 16 + (lane & 15)) v = 0.f;
                }
                acc[m][n][j] = v;
            }
        }
    }

    // ---- fused row/col sums (atomic partials) ----
    if (RSUM == 1) {
#pragma unroll
        for (int m = 0; m < MF; ++m) {
#pragma unroll
            for (int j = 0; j < 4; ++j) {
                float p = 0.f;
#pragma unroll
                for (int n = 0; n < MF; ++n) p += acc[m][n][j];
                p += __shfl_xor(p, 1); p += __shfl_xor(p, 2);
                p += __shfl_xor(p, 4); p += __shfl_xor(p, 8);
                if ((lane & 15) == 0)
                    atomicAdd(rsz + row0 + wr + m * 16 + ((lane >> 4) << 2) + j, p);
            }
        }
    } else if (RSUM == 2) {
#pragma unroll
        for (int n = 0; n < MF; ++n) {
            float p = 0.f;
#pragma unroll
            for (int m = 0; m < MF; ++m)
#pragma unroll
                for (int j = 0; j < 4; ++j) p += acc[m][n][j];
            p += __shfl_xor(p, 16); p += __shfl_xor(p, 32);
            if (lane < 16) atomicAdd(rsz + col0 + wc + n * 16 + lane, p);
        }
    }

    char* lc = reinterpret_cast<char*>(smem);
    if (STORE_N) {
#pragma unroll
        for (int m = 0; m < MF; ++m) {
#pragma unroll
            for (int n = 0; n < MF; ++n) {
#pragma unroll
                for (int j = 0; j < 4; ++j) {
                    int lrow = wr + m * 16 + ((lane >> 4) << 2) + j;
                    int lcol = wc + n * 16 + (lane & 15);
                    u32 byte = (u32)((lrow * BM + lcol) * 2) ^ (((lrow >> 2) & 3) << 5);
                    *reinterpret_cast<u16*>(lc + byte) = f2bf(acc[m][n][j]);
                }
            }
        }
        __syncthreads();
        constexpr int CH = BM / 8;
        constexpr int NIT = BM * CH / 256;
        u16* Cp = reinterpret_cast<u16*>(Cv) + zo * sCz;
#pragma unroll
        for (int it = 0; it < NIT; ++it) {
            int idx = it * 256 + tid;
            int rrow = idx / CH, c8 = idx % CH;
            u32 byte = (u32)((rrow * BM + c8 * 8) * 2) ^ (((rrow >> 2) & 3) << 5);
            u16x8 val = *reinterpret_cast<const u16x8*>(lc + byte);
            *reinterpret_cast<u16x8*>(Cp + (size_t)(row0 + rrow) * ldc + col0 + c8 * 8) = val;
        }
    }
    if (STORE_T) {
        __syncthreads();
#pragma unroll
        for (int m = 0; m < MF; ++m) {
#pragma unroll
            for (int n = 0; n < MF; ++n) {
                int lcol = wc + n * 16 + (lane & 15);
                int lrow0 = wr + m * 16 + ((lane >> 4) << 2);
                u32 byte = (u32)((lcol * BM + lrow0) * 2) ^ ((u32)(lcol & 7) << 4);
                u32 lo = (u32)f2bf(acc[m][n][0]) | ((u32)f2bf(acc[m][n][1]) << 16);
                u32 hi = (u32)f2bf(acc[m][n][2]) | ((u32)f2bf(acc[m][n][3]) << 16);
                uint2 pk; pk.x = lo; pk.y = hi;
                *reinterpret_cast<uint2*>(lc + byte) = pk;
            }
        }
        __syncthreads();
        constexpr int CHT = BM / 8;
        constexpr int NITT = BM * CHT / 256;
        u16* Tp = reinterpret_cast<u16*>(CvT) + zo * sCzT;
#pragma unroll
        for (int it = 0; it < NITT; ++it) {
            int idx = it * 256 + tid;
            int c = idx / CHT, r8 = idx % CHT;
            u32 byte = (u32)((c * BM + r8 * 8) * 2) ^ ((u32)(c & 7) << 4);
            u16x8 val = *reinterpret_cast<const u16x8*>(lc + byte);
            *reinterpret_cast<u16x8*>(Tp + (size_t)(col0 + c) * ldcT + row0 + r8 * 8) = val;
        }
    }
}

// ---------------- stage-2 reduce: out[row][d] = sum_h elu((1/rd_h[row]) * part[h][row][d]) ----------------
__global__ __launch_bounds__(256) void reduce_h_elu_kernel(const u16* __restrict__ part,
                                                           float* __restrict__ out, int R, int H,
                                                           const float* __restrict__ rd) {
    int i = blockIdx.x * 256 + threadIdx.x;
    int row = i >> 6, c8 = i & 63;
    long plane = (long)R * 512;
    const u16* p = part + (size_t)row * 512 + c8 * 8;
    float s[8] = {};
    for (int h = 0; h < H; ++h) {
        u16x8 x = *reinterpret_cast<const u16x8*>(p + (size_t)h * plane);
        float r = rd ? 1.f / rd[(size_t)h * R + row] : 1.f;
#pragma unroll
        for (int j = 0; j < 8; ++j) {
            float v = bf2f(x[j]) * r;
            s[j] += v > 0.f ? v : (__expf(v) - 1.f);
        }
    }
    float4* o = reinterpret_cast<float4*>(out + (size_t)row * 512 + c8 * 8);
    o[0] = float4{s[0], s[1], s[2], s[3]};
    o[1] = float4{s[4], s[5], s[6], s[7]};
}

// ---------------- combines (float4) ----------------
__global__ __launch_bounds__(256) void combine_obj_kernel(const float4* __restrict__ feat,
        const float4* __restrict__ a, const float4* __restrict__ b,
        const float4* __restrict__ c, const float4* __restrict__ d,
        float4* __restrict__ out, ushort4* __restrict__ outbf) {
    int i = blockIdx.x * 256 + threadIdx.x;
    int r = i >> 8, c4 = i & 255;
    size_t half = (size_t)r * 128 + (c4 & 127);
    float4 t1 = (c4 < 128) ? a[half] : b[half];
    float4 t2 = (c4 < 128) ? c[half] : d[half];
    float4 f = feat[i];
    float4 o;
    o.x = (f.x + t1.x + t2.x) * (1.f / 3.f);
    o.y = (f.y + t1.y + t2.y) * (1.f / 3.f);
    o.z = (f.z + t1.z + t2.z) * (1.f / 3.f);
    o.w = (f.w + t1.w + t2.w) * (1.f / 3.f);
    out[i] = o;
    ushort4 ob; ob.x = f2bf(o.x); ob.y = f2bf(o.y); ob.z = f2bf(o.z); ob.w = f2bf(o.w);
    outbf[i] = ob;
}

__global__ __launch_bounds__(256) void combine_rel1_kernel(const float4* __restrict__ feat,
        const float4* __restrict__ a, const float4* __restrict__ b, ushort4* __restrict__ outbf) {
    int i = blockIdx.x * 256 + threadIdx.x;
    int r = i >> 8, c4 = i & 255;
    size_t half = (size_t)r * 128 + (c4 & 127);
    float4 t = (c4 < 128) ? a[half] : b[half];
    float4 f = feat[i];
    ushort4 ob;
    ob.x = f2bf((f.x + t.x) * 0.5f); ob.y = f2bf((f.y + t.y) * 0.5f);
    ob.z = f2bf((f.z + t.z) * 0.5f); ob.w = f2bf((f.w + t.w) * 0.5f);
    outbf[i] = ob;
}

__global__ __launch_bounds__(256) void combine_rel2_kernel(const float4* __restrict__ feat,
        const float4* __restrict__ a, const float4* __restrict__ b, float4* __restrict__ out) {
    int i = blockIdx.x * 256 + threadIdx.x;
    int r = i >> 8, c4 = i & 255;
    size_t half = (size_t)r * 128 + (c4 & 127);
    float4 t = (c4 < 128) ? a[half] : b[half];
    float4 f = feat[i];
    float4 o;
    o.x = (f.x + t.x) * 0.5f; o.y = (f.y + t.y) * 0.5f;
    o.z = (f.z + t.z) * 0.5f; o.w = (f.w + t.w) * 0.5f;
    out[i] = o;
}

extern "C" void kernel_launch(void* const* d_in, const int* in_sizes, int n_in,
                              void* d_out, int out_size, void* d_ws, size_t ws_size,
                              hipStream_t stream) {
    (void)in_sizes; (void)n_in; (void)out_size; (void)ws_size;
    const float* feat_obj = (const float*)d_in[0];
    const float* feat_rel = (const float*)d_in[1];
    const float* W_cat = (const float*)d_in[2];
    const float* b_cat = (const float*)d_in[3];
    const float* W_out = (const float*)d_in[4];
    const float* b_out = (const float*)d_in[5];
    float* out_obj = (float*)d_out;
    float* out_rel = (float*)d_out + (size_t)2048 * 1024;

    char* w = (char*)d_ws;
    auto alloc = [&](size_t bytes) { void* p = (void*)w; w += (bytes + 255) & ~(size_t)255; return p; };
    u16* bf_obj  = (u16*)alloc((size_t)2048 * 1024 * 2);
    u16* bf_rel  = (u16*)alloc((size_t)4096 * 1024 * 2);
    u16* bf_obj2 = (u16*)alloc((size_t)2048 * 1024 * 2);
    u16* bf_rel2 = (u16*)alloc((size_t)4096 * 1024 * 2);
    u16* Wt_cat  = (u16*)alloc((size_t)12 * 512 * 1024 * 2);     // 12 MiB
    // stage-1 projections
    u16* Q01   = (u16*)alloc((size_t)2 * 2048 * 512 * 2);   // z0=m0.q, z1=m1.q
    u16* K02   = (u16*)alloc((size_t)2 * 2048 * 512 * 2);   // z0=m0.k, z1=m2.k
    u16* Q2    = (u16*)alloc((size_t)4096 * 512 * 2);
    u16* K1    = (u16*)alloc((size_t)4096 * 512 * 2);
    u16* Vq01T = (u16*)alloc((size_t)2 * 512 * 2048 * 2);   // z0=m0.qvT, z1=m1.qvT
    u16* Vk02T = (u16*)alloc((size_t)2 * 512 * 2048 * 2);   // z0=m0.kvT, z1=m2.kvT
    u16* Vk1T  = (u16*)alloc((size_t)512 * 4096 * 2);
    u16* Vq2T  = (u16*)alloc((size_t)512 * 4096 * 2);
    // stage-2 buffers
    u16* Pq2   = (u16*)alloc((size_t)2 * 2048 * 3072 * 2);  // z0=mha0.q, z1=mha1.k (obj2 input)
    u16* Pk2   = (u16*)alloc((size_t)2 * 4096 * 3072 * 2);  // z0=mha0.k, z1=mha1.q (rel2 input)
    u16* VTa   = (u16*)alloc((size_t)2 * 3072 * 2048 * 2);  // z0=mha0.qvT, z1=mha1.kvT
    u16* VTs   = (u16*)alloc((size_t)3072 * 2048 * 2);
    u16* Sbuf  = (u16*)alloc((size_t)6 * 4096 * 2048 * 2);  // 96 MiB
    // Wt2 ALIASES Sbuf: written+read before the first Sbuf (score) write.
    u16* Wt2   = Sbuf;                                      // 48 MiB of the 96
    u16* part  = (u16*)alloc((size_t)6 * 4096 * 512 * 2);
    float* rdAll = (float*)alloc((size_t)36864 * 4);
    float* rdQ = rdAll;               // 6*2048
    float* rdM = rdAll + 12288;       // 6*4096
    // stage-1 rsinv (written by fused pass 1, read by scale + pass 2)
    float* rs0 = (float*)alloc((size_t)4 * 2048 * 4);
    float* rs1 = (float*)alloc((size_t)4 * 2048 * 4);
    float* rs2 = (float*)alloc((size_t)4 * 4096 * 4);
    float* sub_obj  = (float*)alloc((size_t)2048 * 512 * 4);
    float* obj_sub  = (float*)alloc((size_t)2048 * 512 * 4);
    float* sub_rel  = (float*)alloc((size_t)2048 * 512 * 4);
    float* obj_rel  = (float*)alloc((size_t)2048 * 512 * 4);
    float* rel_obj  = (float*)alloc((size_t)4096 * 512 * 4);
    float* rel_sub  = (float*)alloc((size_t)4096 * 512 * 4);
    float* rel_obj2 = (float*)alloc((size_t)4096 * 512 * 4);
    float* rel_sub2 = (float*)alloc((size_t)4096 * 512 * 4);

    zero_kernel<<<144, 256, 0, stream>>>(rdAll, 36864);
    cvt_bf16_kernel<<<2048, 256, 0, stream>>>((const float4*)feat_obj, (ushort4*)bf_obj, 2048 * 1024 / 4);
    cvt_bf16_kernel<<<4096, 256, 0, stream>>>((const float4*)feat_rel, (ushort4*)bf_rel, 4096 * 1024 / 4);
    transcvt_kernel<<<dim3(16, 32, 12), dim3(32, 8), 0, stream>>>(W_cat, Wt_cat, 1024, 512);
    transcvt_kernel<<<dim3(96, 32, 8), dim3(32, 8), 0, stream>>>(W_out, Wt2, 1024, 3072);

    const float sc1 = 0.08838834764831845f;  // 1/sqrt(128)
    const float sc2 = 0.04419417382415922f;  // 1/sqrt(512)
    const long planeW = (long)512 * 1024;
    const long planeW2 = (long)3072 * 1024;
    const long NIL = 0;

    // ---------------- stage-1 projections (8 dispatches, z-batched by input+layout) ----------------
    gemm_nt<E_PROJ, 64><<<dim3(32, 8, 2), 256, 0, stream>>>(
        bf_obj, Wt_cat, Q01, nullptr, b_cat, nullptr,
        2048, 512, 1024, 1024, 1024, 512, 0, 0.f, NIL, 4 * planeW, (long)2048 * 512, NIL,
        4L * 512, NIL, 1, NIL, NIL);
    gemm_nt<E_PROJ, 64><<<dim3(32, 8, 2), 256, 0, stream>>>(
        bf_obj, Wt_cat + planeW, K02, nullptr, b_cat + 512, nullptr,
        2048, 512, 1024, 1024, 1024, 512, 0, 0.f, NIL, 8 * planeW, (long)2048 * 512, NIL,
        8L * 512, NIL, 1, NIL, NIL);
    gemm_nt<E_PROJT, 64><<<dim3(32, 8, 2), 256, 0, stream>>>(
        bf_obj, Wt_cat + 2 * planeW, nullptr, Vq01T, b_cat + 1024, nullptr,
        2048, 512, 1024, 1024, 1024, 0, 2048, 0.f, NIL, 4 * planeW, NIL, (long)512 * 2048,
        4L * 512, NIL, 1, NIL, NIL);
    gemm_nt<E_PROJT, 64><<<dim3(32, 8, 2), 256, 0, stream>>>(
        bf_obj, Wt_cat + 3 * planeW, nullptr, Vk02T, b_cat + 1536, nullptr,
        2048, 512, 1024, 1024, 1024, 0, 2048, 0.f, NIL, 8 * planeW, NIL, (long)512 * 2048,
        8L * 512, NIL, 1, NIL, NIL);
    gemm_nt<E_PROJ, 64><<<dim3(64, 8, 1), 256, 0, stream>>>(
        bf_rel, Wt_cat + 5 * planeW, K1, nullptr, b_cat + 5 * 512, nullptr,
        4096, 512, 1024, 1024, 1024, 512, 0, 0.f, NIL, NIL, NIL, NIL, NIL, NIL, 1, NIL, NIL);
    gemm_nt<E_PROJ, 64><<<dim3(64, 8, 1), 256, 0, stream>>>(
        bf_rel, Wt_cat + 8 * planeW, Q2, nullptr, b_cat + 8 * 512, nullptr,
        4096, 512, 1024, 1024, 1024, 512, 0, 0.f, NIL, NIL, NIL, NIL, NIL, NIL, 1, NIL, NIL);
    gemm_nt<E_PROJT, 64><<<dim3(64, 8, 1), 256, 0, stream>>>(
        bf_rel, Wt_cat + 7 * planeW, nullptr, Vk1T, b_cat + 7 * 512, nullptr,
        4096, 512, 1024, 1024, 1024, 0, 4096, 0.f, NIL, NIL, NIL, NIL, NIL, NIL, 1, NIL, NIL);
    gemm_nt<E_PROJT, 64><<<dim3(64, 8, 1), 256, 0, stream>>>(
        bf_rel, Wt_cat + 10 * planeW, nullptr, Vq2T, b_cat + 10 * 512, nullptr,
        4096, 512, 1024, 1024, 1024, 0, 4096, 0.f, NIL, NIL, NIL, NIL, NIL, NIL, 1, NIL, NIL);

    // ---------------- fused stage-1 attention ----------------
    FCfg f1, f2;
    f1.g[0] = { Q01,                    K02,                    Vk02T,                    sub_obj, rs0, 2048, 2048, 1 };
    f1.g[1] = { Q01 + (size_t)2048*512, K1,                     Vk1T,                     sub_rel, rs1, 2048, 4096, 0 };
    f1.g[2] = { Q2,                     K02 + (size_t)2048*512, Vk02T + (size_t)512*2048, rel_obj, rs2, 4096, 2048, 0 };
    fused_attn1_kernel<1><<<dim3(64, 1, 12), 256, 0, stream>>>(f1, sc1);
    // pre-scale pass-2 V buffers by rsinv (per key-column); in-place
    scale_rows_kernel<<<512, 256, 0, stream>>>(Vq01T, Vq01T, rs0, 2048, 7, 1);
    scale_rows_kernel<<<512, 256, 0, stream>>>(Vq01T + (size_t)512 * 2048, Vq01T + (size_t)512 * 2048, rs1, 2048, 7, 1);
    scale_rows_kernel<<<1024, 256, 0, stream>>>(Vq2T, Vq2T, rs2, 4096, 7, 1);
    f2.g[0] = { K02,                    Q01,                    Vq01T,                    obj_sub, rs0, 2048, 2048, 1 };
    f2.g[1] = { K1,                     Q01 + (size_t)2048*512, Vq01T + (size_t)512*2048, rel_sub, rs1, 4096, 2048, 0 };
    f2.g[2] = { K02 + (size_t)2048*512, Q2,                     Vq2T,                     obj_rel, rs2, 2048, 4096, 0 };
    fused_attn1_kernel<0><<<dim3(64, 1, 12), 256, 0, stream>>>(f2, sc1);

    combine_obj_kernel<<<2048, 256, 0, stream>>>((const float4*)feat_obj, (const float4*)sub_obj,
        (const float4*)obj_sub, (const float4*)sub_rel, (const float4*)obj_rel,
        (float4*)out_obj, (ushort4*)bf_obj2);
    combine_rel1_kernel<<<4096, 256, 0, stream>>>((const float4*)feat_rel, (const float4*)rel_obj,
        (const float4*)rel_sub, (ushort4*)bf_rel2);

    // ---------------- stage-2 projections (3 dispatches; read Wt2 BEFORE Sbuf writes) ----------------
    gemm_nt<E_PROJ, 128><<<dim3(16, 24, 2), 256, 0, stream>>>(
        bf_obj2, Wt2, Pq2, nullptr, b_out, nullptr,
        2048, 3072, 1024, 1024, 1024, 3072, 0, 0.f, NIL, 5 * planeW2, (long)2048 * 3072, NIL,
        5L * 3072, NIL, 1, NIL, NIL);
    gemm_nt<E_PROJ, 128><<<dim3(32, 24, 2), 256, 0, stream>>>(
        bf_rel2, Wt2 + planeW2, Pk2, nullptr, b_out + 3072, nullptr,
        4096, 3072, 1024, 1024, 1024, 3072, 0, 0.f, NIL, 3 * planeW2, (long)4096 * 3072, NIL,
        3L * 3072, NIL, 1, NIL, NIL);
    gemm_nt<E_PROJT, 128><<<dim3(16, 24, 2), 256, 0, stream>>>(
        bf_obj2, Wt2 + 2 * planeW2, nullptr, VTa, b_out + 2 * 3072, nullptr,
        2048, 3072, 1024, 1024, 1024, 0, 2048, 0.f, NIL, 5 * planeW2, NIL, (long)3072 * 2048,
        5L * 3072, NIL, 1, NIL, NIL);

    const long spl2 = (long)4096 * 2048;
    const long vpl2 = (long)4096 * 512;

    // ---------------- stage 2 mha0: a2 only (swapped scores) ----------------
    {
        gemm_nt<E_EXPC, 128><<<dim3(32, 16, 6), 256, 0, stream>>>(
            Pk2, Pq2, Sbuf, nullptr, nullptr, rdQ,
            4096, 2048, 512, 3072, 3072, 2048, 0, sc2, 512, 512, spl2, NIL, NIL, 2048, 1, NIL, NIL);
        scale_rows_kernel<<<3072, 256, 0, stream>>>(VTa, VTs, rdQ, 2048, 9, 0);
        gemm_nt<E_PART, 128><<<dim3(32, 4, 6), 256, 0, stream>>>(
            Sbuf, VTs, part, nullptr, nullptr, nullptr,
            4096, 512, 2048, 2048, 2048, 512, 0, 0.f, spl2, 512L * 2048, vpl2, NIL, NIL, NIL,
            1, NIL, NIL);
        reduce_h_elu_kernel<<<1024, 256, 0, stream>>>(part, rel_sub2, 4096, 6, nullptr);
    }
    // ---------------- stage 2 mha1: a1 only ----------------
    {
        gemm_nt<E_EXP, 128><<<dim3(32, 16, 6), 256, 0, stream>>>(
            Pk2 + (size_t)4096 * 3072, Pq2 + (size_t)2048 * 3072, Sbuf, nullptr, nullptr, rdM,
            4096, 2048, 512, 3072, 3072, 2048, 0, sc2, 512, 512, spl2, NIL, NIL, 4096, 1, NIL, NIL);
        gemm_nt<E_PART, 128><<<dim3(32, 4, 6), 256, 0, stream>>>(
            Sbuf, VTa + (size_t)3072 * 2048, part, nullptr, nullptr, nullptr,
            4096, 512, 2048, 2048, 2048, 512, 0, 0.f, spl2, 512L * 2048, vpl2, NIL, NIL, NIL,
            1, NIL, NIL);
        reduce_h_elu_kernel<<<1024, 256, 0, stream>>>(part, rel_obj2, 4096, 6, rdM);
    }

    combine_rel2_kernel<<<4096, 256, 0, stream>>>((const float4*)feat_rel, (const float4*)rel_obj2,
        (const float4*)rel_sub2, (float4*)out_rel);
}

// Round 14
// 792.272 us; speedup vs baseline: 1.0327x; 1.0327x over previous
//
#include <hip/hip_runtime.h>

typedef unsigned short u16;
typedef unsigned int u32;
typedef __attribute__((ext_vector_type(4))) float f32x4;
typedef __attribute__((ext_vector_type(8))) __bf16 bf16x8;
typedef __attribute__((ext_vector_type(8))) unsigned short u16x8;

#if defined(__has_builtin)
#if __has_builtin(__builtin_amdgcn_global_load_lds)
#define HAS_GLL 1
#endif
#endif

__device__ __forceinline__ u16 f2bf(float f) {
    u32 u = __builtin_bit_cast(u32, f);
    u += 0x7fffu + ((u >> 16) & 1u);
    return (u16)(u >> 16);
}
__device__ __forceinline__ float bf2f(u16 x) {
    return __builtin_bit_cast(float, (u32)x << 16);
}

// counted-vmcnt barrier
template <int N> __device__ __forceinline__ void wbar() {
#ifdef HAS_GLL
    if constexpr (N == 0)
        asm volatile("s_waitcnt vmcnt(0)\n\ts_barrier" ::: "memory");
    else if constexpr (N == 2)
        asm volatile("s_waitcnt vmcnt(2)\n\ts_barrier" ::: "memory");
    else
        asm volatile("s_waitcnt vmcnt(4)\n\ts_barrier" ::: "memory");
#else
    __syncthreads();
#endif
}

__device__ __forceinline__ void fbar() {
#ifdef HAS_GLL
    asm volatile("s_waitcnt vmcnt(0) lgkmcnt(0)\n\ts_barrier" ::: "memory");
#else
    __syncthreads();
#endif
}

__device__ __forceinline__ void lbar() {
#ifdef HAS_GLL
    asm volatile("s_waitcnt lgkmcnt(0)\n\ts_barrier" ::: "memory");
#else
    __syncthreads();
#endif
}

// stage-1 weight-plane permutation: src plane (mha*4+j) -> grouped dest plane
__device__ __forceinline__ int s1perm(int b) {
    switch (b) {
        case 0: return 0;  case 1: return 2;  case 2: return 4;  case 3: return 6;
        case 4: return 1;  case 5: return 8;  case 6: return 5;  case 7: return 10;
        case 8: return 9;  case 9: return 3;  case 10: return 11; default: return 7;
    }
}

// ---------------- utility kernels ----------------
__global__ __launch_bounds__(256) void zero_kernel(float* __restrict__ p, int n) {
    int i = blockIdx.x * 256 + threadIdx.x;
    if (i < n) p[i] = 0.f;
}

__global__ __launch_bounds__(256) void cvt_bf16_kernel(const float4* __restrict__ in,
                                                       ushort4* __restrict__ out, int n4) {
    int i = blockIdx.x * 256 + threadIdx.x;
    if (i < n4) {
        float4 v = in[i];
        ushort4 o;
        o.x = f2bf(v.x); o.y = f2bf(v.y); o.z = f2bf(v.z); o.w = f2bf(v.w);
        out[i] = o;
    }
}

// transpose + convert: W [B][K][N] f32 -> Wt [B][N][K] bf16
__global__ __launch_bounds__(256) void transcvt_kernel(const float* __restrict__ W,
                                                       u16* __restrict__ Wt, int K, int N) {
    __shared__ u16 t[32][33];
    int b = blockIdx.z;
    const float* Wb = W + (size_t)b * K * N;
    u16* Wtb = Wt + (size_t)b * K * N;
    int n0 = blockIdx.x * 32, k0 = blockIdx.y * 32;
    int tx = threadIdx.x, ty = threadIdx.y;
#pragma unroll
    for (int j = 0; j < 4; ++j)
        t[ty + j * 8][tx] = f2bf(Wb[(size_t)(k0 + ty + j * 8) * N + n0 + tx]);
    __syncthreads();
#pragma unroll
    for (int j = 0; j < 4; ++j)
        Wtb[(size_t)(n0 + ty + j * 8) * K + k0 + tx] = t[tx][ty + j * 8];
}

// same, but dest plane permuted per s1perm
__global__ __launch_bounds__(256) void transcvt_perm_kernel(const float* __restrict__ W,
                                                            u16* __restrict__ Wt, int K, int N) {
    __shared__ u16 t[32][33];
    int b = blockIdx.z;
    int d = s1perm(b);
    const float* Wb = W + (size_t)b * K * N;
    u16* Wtb = Wt + (size_t)d * K * N;
    int n0 = blockIdx.x * 32, k0 = blockIdx.y * 32;
    int tx = threadIdx.x, ty = threadIdx.y;
#pragma unroll
    for (int j = 0; j < 4; ++j)
        t[ty + j * 8][tx] = f2bf(Wb[(size_t)(k0 + ty + j * 8) * N + n0 + tx]);
    __syncthreads();
#pragma unroll
    for (int j = 0; j < 4; ++j)
        Wtb[(size_t)(n0 + ty + j * 8) * K + k0 + tx] = t[tx][ty + j * 8];
}

// permute stage-1 biases: out[perm(b)*512+i] = in[b*512+i]; one block per src plane
__global__ __launch_bounds__(256) void bias_perm_kernel(const float* __restrict__ in,
                                                        float* __restrict__ out) {
    int b = blockIdx.x;
    int d = s1perm(b);
    out[d * 512 + threadIdx.x] = in[b * 512 + threadIdx.x];
    out[d * 512 + 256 + threadIdx.x] = in[b * 512 + 256 + threadIdx.x];
}

// ---------------- scale rows of [R][C] bf16 by rd[(r>>lg)*C + c]: mul ? * : / ----------------
__global__ __launch_bounds__(256) void scale_rows_kernel(const u16* __restrict__ in,
                                                         u16* __restrict__ out,
                                                         const float* __restrict__ rd,
                                                         int C, int lgdk, int mul) {
    int i = (blockIdx.x * 256 + threadIdx.x) * 8;
    int r = i / C, c = i % C;
    const float* rdp = rd + ((size_t)(r >> lgdk)) * C + c;
    u16x8 x = *reinterpret_cast<const u16x8*>(in + i);
    u16x8 o;
#pragma unroll
    for (int j = 0; j < 8; ++j)
        o[j] = f2bf(mul ? bf2f(x[j]) * rdp[j] : bf2f(x[j]) / rdp[j]);
    *reinterpret_cast<u16x8*>(out + i) = o;
}

// ---------------- fused stage-1 attention v2 (A in regs, B/V dbuf, counted vmcnt) ----------------
struct FGrp { const u16* A; const u16* B; const u16* V; float* O; float* rs; int M; int NK; int mask; };
struct FCfg { FGrp g[3]; };

template <int NORM>
__global__ __launch_bounds__(256) void fused_attn1_kernel(FCfg cfg, float scale) {
    __shared__ __align__(16) u16 Bbuf[2][4 * 2048];
    __shared__ __align__(16) u16 Vbuf[2][2 * 4096];
    __shared__ __align__(16) u16 Pbuf[2 * 2048];
    __shared__ float rsum_lds[64][2];
    const int gi = blockIdx.z >> 2, h = blockIdx.z & 3;
    FGrp G = (gi == 0) ? cfg.g[0] : (gi == 1) ? cfg.g[1] : cfg.g[2];
    const int row0 = blockIdx.x * 64;
    if (row0 >= G.M) return;
    const u16* Ap = G.A + h * 128;
    const u16* Bp = G.B + h * 128;
    const u16* Vp = G.V + (size_t)h * 128 * G.NK;
    float* Op = G.O + h * 128;
    const int ldv = G.NK;
    const int tid = threadIdx.x, lane = tid & 63, wid = tid >> 6;
    const int swr = (wid >> 1) * 32, swc = (wid & 1) * 32;
    const int pwr = swr, pwc = (wid & 1) * 64;

    auto gld = [&](const u16* src, u16* dst) {
#ifdef HAS_GLL
        __builtin_amdgcn_global_load_lds(
            (const __attribute__((address_space(1))) void*)src,
            (__attribute__((address_space(3))) void*)dst, 16, 0, 0);
#else
        *reinterpret_cast<uint4*>(dst) = *reinterpret_cast<const uint4*>(src);
#endif
    };
    auto stageB = [&](int t, int buf) {
#pragma unroll
        for (int it = 0; it < 4; ++it) {
            int c = tid + it * 256;
            int kb = c >> 8, cc = c & 255;
            int r = cc >> 2, lch = (cc & 3) ^ ((r >> 1) & 3);
            gld(Bp + (size_t)(t * 64 + r) * 512 + kb * 32 + lch * 8, &Bbuf[buf][kb * 2048 + cc * 8]);
        }
    };
    auto stageV = [&](int t, int buf) {
#pragma unroll
        for (int it = 0; it < 4; ++it) {
            int c = tid + it * 256;
            int kb = c >> 9, cc = c & 511;
            int r = cc >> 2, lch = (cc & 3) ^ ((r >> 1) & 3);
            gld(Vp + (size_t)r * ldv + t * 64 + kb * 32 + lch * 8, &Vbuf[buf][kb * 4096 + cc * 8]);
        }
    };

    bf16x8 areg[2][4];
#pragma unroll
    for (int m = 0; m < 2; ++m) {
        int rr = swr + m * 16 + (lane & 15);
#pragma unroll
        for (int kk = 0; kk < 4; ++kk)
            areg[m][kk] = *reinterpret_cast<const bf16x8*>(
                Ap + (size_t)(row0 + rr) * 512 + kk * 32 + (lane >> 4) * 8);
    }
    stageB(0, 0);
    stageV(0, 0);
    stageB(1, 1);
    stageV(1, 1);
    fbar();

    f32x4 accp[2][4] = {};
    float rsum[2][4] = {};
    const int nt = G.NK >> 6;
    for (int t = 0; t < nt; ++t) {
        const int cur = t & 1;
        f32x4 accs[2][2] = {};
#pragma unroll
        for (int kk = 0; kk < 4; ++kk) {
            bf16x8 bf[2];
#pragma unroll
            for (int n = 0; n < 2; ++n) {
                int rr = swc + n * 16 + (lane & 15);
                int p = (lane >> 4) ^ ((rr >> 1) & 3);
                bf[n] = *reinterpret_cast<const bf16x8*>(&Bbuf[cur][kk * 2048 + rr * 32 + p * 8]);
            }
#pragma unroll
            for (int m = 0; m < 2; ++m)
#pragma unroll
                for (int n = 0; n < 2; ++n)
                    accs[m][n] = __builtin_amdgcn_mfma_f32_16x16x32_bf16(areg[m][kk], bf[n], accs[m][n], 0, 0, 0);
        }
#pragma unroll
        for (int m = 0; m < 2; ++m) {
#pragma unroll
            for (int n = 0; n < 2; ++n) {
#pragma unroll
                for (int j = 0; j < 4; ++j) {
                    int prow = swr + m * 16 + ((lane >> 4) << 2) + j;
                    int pkey = swc + n * 16 + (lane & 15);
                    float v = __expf(accs[m][n][j] * scale);
                    if (G.mask && (row0 + prow == t * 64 + pkey)) v = 0.f;
                    if (NORM == 1) rsum[m][j] += v;
                    Pbuf[(pkey >> 5) * 2048 + prow * 32 +
                         ((((pkey >> 3) & 3) ^ ((prow >> 1) & 3)) << 3) + (pkey & 7)] = f2bf(v);
                }
            }
        }
        lbar();
        if (t + 2 < nt) stageB(t + 2, cur);
#pragma unroll
        for (int kk = 0; kk < 2; ++kk) {
            bf16x8 pf[2], vf[4];
#pragma unroll
            for (int m = 0; m < 2; ++m) {
                int rr = pwr + m * 16 + (lane & 15);
                int p = (lane >> 4) ^ ((rr >> 1) & 3);
                pf[m] = *reinterpret_cast<const bf16x8*>(&Pbuf[kk * 2048 + rr * 32 + p * 8]);
            }
#pragma unroll
            for (int n = 0; n < 4; ++n) {
                int dd = pwc + n * 16 + (lane & 15);
                int p = (lane >> 4) ^ ((dd >> 1) & 3);
                vf[n] = *reinterpret_cast<const bf16x8*>(&Vbuf[cur][kk * 4096 + dd * 32 + p * 8]);
            }
#pragma unroll
            for (int m = 0; m < 2; ++m)
#pragma unroll
                for (int n = 0; n < 4; ++n)
                    accp[m][n] = __builtin_amdgcn_mfma_f32_16x16x32_bf16(pf[m], vf[n], accp[m][n], 0, 0, 0);
        }
        if (t + 2 < nt)      wbar<4>();
        else if (t + 1 < nt) wbar<0>();
        if (t + 2 < nt) stageV(t + 2, cur);
    }

    if (NORM == 1) {
#pragma unroll
        for (int m = 0; m < 2; ++m)
#pragma unroll
            for (int j = 0; j < 4; ++j) {
                float s = rsum[m][j];
                s += __shfl_xor(s, 1); s += __shfl_xor(s, 2);
                s += __shfl_xor(s, 4); s += __shfl_xor(s, 8);
                rsum[m][j] = s;
            }
        if ((lane & 15) == 0) {
#pragma unroll
            for (int m = 0; m < 2; ++m)
#pragma unroll
                for (int j = 0; j < 4; ++j)
                    rsum_lds[swr + m * 16 + ((lane >> 4) << 2) + j][wid & 1] = rsum[m][j];
        }
        __syncthreads();
        if (tid < 64)
            G.rs[(size_t)h * G.M + row0 + tid] = 1.f / (rsum_lds[tid][0] + rsum_lds[tid][1]);
#pragma unroll
        for (int m = 0; m < 2; ++m) {
#pragma unroll
            for (int j = 0; j < 4; ++j) {
                int row = pwr + m * 16 + ((lane >> 4) << 2) + j;
                float rd = 1.f / (rsum_lds[row][0] + rsum_lds[row][1]);
#pragma unroll
                for (int n = 0; n < 4; ++n) {
                    float v = accp[m][n][j] * rd;
                    v = v > 0.f ? v : (__expf(v) - 1.f);
                    Op[(size_t)(row0 + row) * 512 + pwc + n * 16 + (lane & 15)] = v;
                }
            }
        }
    } else {
#pragma unroll
        for (int m = 0; m < 2; ++m) {
#pragma unroll
            for (int j = 0; j < 4; ++j) {
                int row = pwr + m * 16 + ((lane >> 4) << 2) + j;
#pragma unroll
                for (int n = 0; n < 4; ++n) {
                    float v = accp[m][n][j];
                    v = v > 0.f ? v : (__expf(v) - 1.f);
                    Op[(size_t)(row0 + row) * 512 + pwc + n * 16 + (lane & 15)] = v;
                }
            }
        }
    }
}

// ---------------- GEMM: C = A (M,K) * B^T (N,K), row-major, 3-ring counted-vmcnt ----------------
enum { E_PROJ = 0, E_PROJT, E_EXP, E_EXPC, E_EXPT, E_EXPMT, E_PART };

template <int EPI, int BM>
__global__ __launch_bounds__(256) void gemm_nt(const u16* __restrict__ A, const u16* __restrict__ B,
                                               void* __restrict__ Cv, void* __restrict__ CvT,
                                               const float* __restrict__ bias, float* __restrict__ rs,
                                               int M, int N, int K, int lda, int ldb, int ldc, int ldcT,
                                               float scale, long sAz, long sBz, long sCz, long sCzT,
                                               long sBias, long sRs, int ZK, long sAz2, long sBz2) {
    constexpr bool HAS_BIAS = (EPI == E_PROJ || EPI == E_PROJT);
    constexpr bool DO_EXP = (EPI == E_EXP || EPI == E_EXPC || EPI == E_EXPT || EPI == E_EXPMT);
    constexpr bool DO_MASK = (EPI == E_EXPMT);
    constexpr int RSUM = (EPI == E_EXPC) ? 2 : (DO_EXP ? 1 : 0);
    constexpr bool STORE_N = (EPI != E_PROJT);
    constexpr bool STORE_T = (EPI == E_PROJT || EPI == E_EXPT || EPI == E_EXPMT);

    constexpr int MF = BM / 32;
    constexpr int ITERS = BM * 32 / (256 * 8);
    constexpr int LOADS = ITERS * 2;
    constexpr int SM_STAGE = 3 * BM * 64;
    constexpr int SM_REPACK = BM * BM;
    __shared__ __align__(16) u16 smem[SM_STAGE > SM_REPACK ? SM_STAGE : SM_REPACK];
    const int tid = threadIdx.x;
    const int lane = tid & 63;
    const int wid = tid >> 6;
    const int wr = (wid >> 1) * (BM / 2);
    const int wc = (wid & 1) * (BM / 2);
    const int row0 = blockIdx.x * BM;
    const int col0 = blockIdx.y * BM;
    const long zo = blockIdx.z;
    const long hz = zo / ZK;
    const long kz = zo - hz * ZK;
    const u16* Az = A + hz * sAz + kz * sAz2;
    const u16* Bz = B + hz * sBz + kz * sBz2;
    const float* biasz = bias ? bias + zo * sBias : nullptr;
    float* rsz = rs ? rs + zo * sRs : nullptr;
    f32x4 acc[MF][MF] = {};

    auto As = [&](int buf) { return smem + buf * (BM * 64); };
    auto Bs = [&](int buf) { return smem + buf * (BM * 64) + BM * 32; };

    auto stage = [&](int buf, int k0) {
#pragma unroll
        for (int i = 0; i < ITERS; ++i) {
            int c = tid + i * 256;
            int r = c >> 2;
            int lch = (c & 3) ^ ((r >> 1) & 3);
            const u16* sa = Az + (size_t)(row0 + r) * lda + k0 + lch * 8;
            const u16* sb = Bz + (size_t)(col0 + r) * ldb + k0 + lch * 8;
#ifdef HAS_GLL
            __builtin_amdgcn_global_load_lds(
                (const __attribute__((address_space(1))) void*)sa,
                (__attribute__((address_space(3))) void*)(&As(buf)[c * 8]), 16, 0, 0);
            __builtin_amdgcn_global_load_lds(
                (const __attribute__((address_space(1))) void*)sb,
                (__attribute__((address_space(3))) void*)(&Bs(buf)[c * 8]), 16, 0, 0);
#else
            *reinterpret_cast<uint4*>(&As(buf)[c * 8]) = *reinterpret_cast<const uint4*>(sa);
            *reinterpret_cast<uint4*>(&Bs(buf)[c * 8]) = *reinterpret_cast<const uint4*>(sb);
#endif
        }
    };

    stage(0, 0);
    stage(1, 32);
    wbar<LOADS>();

    const int nsteps = K >> 5;
    for (int t = 0; t < nsteps; ++t) {
        const int bufc = t % 3;
        const bool more2 = (t + 2 < nsteps);
        if (more2) stage((t + 2) % 3, (t + 2) << 5);
        bf16x8 af[MF], bv[MF];
#pragma unroll
        for (int m = 0; m < MF; ++m) {
            int rr = wr + m * 16 + (lane & 15);
            int p = (lane >> 4) ^ ((rr >> 1) & 3);
            af[m] = *reinterpret_cast<const bf16x8*>(&As(bufc)[rr * 32 + p * 8]);
        }
#pragma unroll
        for (int n = 0; n < MF; ++n) {
            int rr = wc + n * 16 + (lane & 15);
            int p = (lane >> 4) ^ ((rr >> 1) & 3);
            bv[n] = *reinterpret_cast<const bf16x8*>(&Bs(bufc)[rr * 32 + p * 8]);
        }
#pragma unroll
        for (int m = 0; m < MF; ++m)
#pragma unroll
            for (int n = 0; n < MF; ++n)
                acc[m][n] = __builtin_amdgcn_mfma_f32_16x16x32_bf16(af[m], bv[n], acc[m][n], 0, 0, 0);
        if (more2)                 wbar<LOADS>();
        else if (t + 1 < nsteps)   wbar<0>();
        else                       __syncthreads();
    }

    // ---- math pass ----
#pragma unroll
    for (int m = 0; m < MF; ++m) {
#pragma unroll
        for (int n = 0; n < MF; ++n) {
#pragma unroll
            for (int j = 0; j < 4; ++j) {
                float v = acc[m][n][j];
                if (HAS_BIAS) v += biasz[col0 + wc + n * 16 + (lane & 15)];
                if (DO_EXP) {
                    v = __expf(v * scale);
                    if (DO_MASK &&
                        row0 + wr + m * 16 + ((lane >> 4) << 2) + j ==
                        col0 + wc + n * 16 + (lane & 15)) v = 0.f;
                }
                acc[m][n][j] = v;
            }
        }
    }

    if (RSUM == 1) {
#pragma unroll
        for (int m = 0; m < MF; ++m) {
#pragma unroll
            for (int j = 0; j < 4; ++j) {
                float p = 0.f;
#pragma unroll
                for (int n = 0; n < MF; ++n) p += acc[m][n][j];
                p += __shfl_xor(p, 1); p += __shfl_xor(p, 2);
                p += __shfl_xor(p, 4); p += __shfl_xor(p, 8);
                if ((lane & 15) == 0)
                    atomicAdd(rsz + row0 + wr + m * 16 + ((lane >> 4) << 2) + j, p);
            }
        }
    } else if (RSUM == 2) {
#pragma unroll
        for (int n = 0; n < MF; ++n) {
            float p = 0.f;
#pragma unroll
            for (int m = 0; m < MF; ++m)
#pragma unroll
                for (int j = 0; j < 4; ++j) p += acc[m][n][j];
            p += __shfl_xor(p, 16); p += __shfl_xor(p, 32);
            if (lane < 16) atomicAdd(rsz + col0 + wc + n * 16 + lane, p);
        }
    }

    char* lc = reinterpret_cast<char*>(smem);
    if (STORE_N) {
#pragma unroll
        for (int m = 0; m < MF; ++m) {
#pragma unroll
            for (int n = 0; n < MF; ++n) {
#pragma unroll
                for (int j = 0; j < 4; ++j) {
                    int lrow = wr + m * 16 + ((lane >> 4) << 2) + j;
                    int lcol = wc + n * 16 + (lane & 15);
                    u32 byte = (u32)((lrow * BM + lcol) * 2) ^ (((lrow >> 2) & 3) << 5);
                    *reinterpret_cast<u16*>(lc + byte) = f2bf(acc[m][n][j]);
                }
            }
        }
        __syncthreads();
        constexpr int CH = BM / 8;
        constexpr int NIT = BM * CH / 256;
        u16* Cp = reinterpret_cast<u16*>(Cv) + zo * sCz;
#pragma unroll
        for (int it = 0; it < NIT; ++it) {
            int idx = it * 256 + tid;
            int rrow = idx / CH, c8 = idx % CH;
            u32 byte = (u32)((rrow * BM + c8 * 8) * 2) ^ (((rrow >> 2) & 3) << 5);
            u16x8 val = *reinterpret_cast<const u16x8*>(lc + byte);
            *reinterpret_cast<u16x8*>(Cp + (size_t)(row0 + rrow) * ldc + col0 + c8 * 8) = val;
        }
    }
    if (STORE_T) {
        __syncthreads();
#pragma unroll
        for (int m = 0; m < MF; ++m) {
#pragma unroll
            for (int n = 0; n < MF; ++n) {
                int lcol = wc + n * 16 + (lane & 15);
                int lrow0 = wr + m * 16 + ((lane >> 4) << 2);
                u32 byte = (u32)((lcol * BM + lrow0) * 2) ^ ((u32)(lcol & 7) << 4);
                u32 lo = (u32)f2bf(acc[m][n][0]) | ((u32)f2bf(acc[m][n][1]) << 16);
                u32 hi = (u32)f2bf(acc[m][n][2]) | ((u32)f2bf(acc[m][n][3]) << 16);
                uint2 pk; pk.x = lo; pk.y = hi;
                *reinterpret_cast<uint2*>(lc + byte) = pk;
            }
        }
        __syncthreads();
        constexpr int CHT = BM / 8;
        constexpr int NITT = BM * CHT / 256;
        u16* Tp = reinterpret_cast<u16*>(CvT) + zo * sCzT;
#pragma unroll
        for (int it = 0; it < NITT; ++it) {
            int idx = it * 256 + tid;
            int c = idx / CHT, r8 = idx % CHT;
            u32 byte = (u32)((c * BM + r8 * 8) * 2) ^ ((u32)(c & 7) << 4);
            u16x8 val = *reinterpret_cast<const u16x8*>(lc + byte);
            *reinterpret_cast<u16x8*>(Tp + (size_t)(col0 + c) * ldcT + row0 + r8 * 8) = val;
        }
    }
}

// ---------------- stage-2 reduce ----------------
__global__ __launch_bounds__(256) void reduce_h_elu_kernel(const u16* __restrict__ part,
                                                           float* __restrict__ out, int R, int H,
                                                           const float* __restrict__ rd) {
    int i = blockIdx.x * 256 + threadIdx.x;
    int row = i >> 6, c8 = i & 63;
    long plane = (long)R * 512;
    const u16* p = part + (size_t)row * 512 + c8 * 8;
    float s[8] = {};
    for (int h = 0; h < H; ++h) {
        u16x8 x = *reinterpret_cast<const u16x8*>(p + (size_t)h * plane);
        float r = rd ? 1.f / rd[(size_t)h * R + row] : 1.f;
#pragma unroll
        for (int j = 0; j < 8; ++j) {
            float v = bf2f(x[j]) * r;
            s[j] += v > 0.f ? v : (__expf(v) - 1.f);
        }
    }
    float4* o = reinterpret_cast<float4*>(out + (size_t)row * 512 + c8 * 8);
    o[0] = float4{s[0], s[1], s[2], s[3]};
    o[1] = float4{s[4], s[5], s[6], s[7]};
}

// ---------------- combines (float4) ----------------
__global__ __launch_bounds__(256) void combine_obj_kernel(const float4* __restrict__ feat,
        const float4* __restrict__ a, const float4* __restrict__ b,
        const float4* __restrict__ c, const float4* __restrict__ d,
        float4* __restrict__ out, ushort4* __restrict__ outbf) {
    int i = blockIdx.x * 256 + threadIdx.x;
    int r = i >> 8, c4 = i & 255;
    size_t half = (size_t)r * 128 + (c4 & 127);
    float4 t1 = (c4 < 128) ? a[half] : b[half];
    float4 t2 = (c4 < 128) ? c[half] : d[half];
    float4 f = feat[i];
    float4 o;
    o.x = (f.x + t1.x + t2.x) * (1.f / 3.f);
    o.y = (f.y + t1.y + t2.y) * (1.f / 3.f);
    o.z = (f.z + t1.z + t2.z) * (1.f / 3.f);
    o.w = (f.w + t1.w + t2.w) * (1.f / 3.f);
    out[i] = o;
    ushort4 ob; ob.x = f2bf(o.x); ob.y = f2bf(o.y); ob.z = f2bf(o.z); ob.w = f2bf(o.w);
    outbf[i] = ob;
}

__global__ __launch_bounds__(256) void combine_rel1_kernel(const float4* __restrict__ feat,
        const float4* __restrict__ a, const float4* __restrict__ b, ushort4* __restrict__ outbf) {
    int i = blockIdx.x * 256 + threadIdx.x;
    int r = i >> 8, c4 = i & 255;
    size_t half = (size_t)r * 128 + (c4 & 127);
    float4 t = (c4 < 128) ? a[half] : b[half];
    float4 f = feat[i];
    ushort4 ob;
    ob.x = f2bf((f.x + t.x) * 0.5f); ob.y = f2bf((f.y + t.y) * 0.5f);
    ob.z = f2bf((f.z + t.z) * 0.5f); ob.w = f2bf((f.w + t.w) * 0.5f);
    outbf[i] = ob;
}

__global__ __launch_bounds__(256) void combine_rel2_kernel(const float4* __restrict__ feat,
        const float4* __restrict__ a, const float4* __restrict__ b, float4* __restrict__ out) {
    int i = blockIdx.x * 256 + threadIdx.x;
    int r = i >> 8, c4 = i & 255;
    size_t half = (size_t)r * 128 + (c4 & 127);
    float4 t = (c4 < 128) ? a[half] : b[half];
    float4 f = feat[i];
    float4 o;
    o.x = (f.x + t.x) * 0.5f; o.y = (f.y + t.y) * 0.5f;
    o.z = (f.z + t.z) * 0.5f; o.w = (f.w + t.w) * 0.5f;
    out[i] = o;
}

extern "C" void kernel_launch(void* const* d_in, const int* in_sizes, int n_in,
                              void* d_out, int out_size, void* d_ws, size_t ws_size,
                              hipStream_t stream) {
    (void)in_sizes; (void)n_in; (void)out_size; (void)ws_size;
    const float* feat_obj = (const float*)d_in[0];
    const float* feat_rel = (const float*)d_in[1];
    const float* W_cat = (const float*)d_in[2];
    const float* b_cat = (const float*)d_in[3];
    const float* W_out = (const float*)d_in[4];
    const float* b_out = (const float*)d_in[5];
    float* out_obj = (float*)d_out;
    float* out_rel = (float*)d_out + (size_t)2048 * 1024;

    char* w = (char*)d_ws;
    auto alloc = [&](size_t bytes) { void* p = (void*)w; w += (bytes + 255) & ~(size_t)255; return p; };
    u16* bf_obj  = (u16*)alloc((size_t)2048 * 1024 * 2);
    u16* bf_rel  = (u16*)alloc((size_t)4096 * 1024 * 2);
    u16* bf_obj2 = (u16*)alloc((size_t)2048 * 1024 * 2);
    u16* bf_rel2 = (u16*)alloc((size_t)4096 * 1024 * 2);
    u16* WtP     = (u16*)alloc((size_t)12 * 512 * 1024 * 2);   // permuted stage-1 weights
    float* rbcat = (float*)alloc((size_t)12 * 512 * 4);        // permuted stage-1 biases
    // stage-1 projections, grouped: QKo[4]: m0.q, m1.q, m0.k, m2.k (2048x512 each)
    u16* QKo   = (u16*)alloc((size_t)4 * 2048 * 512 * 2);
    u16* RelN  = (u16*)alloc((size_t)2 * 4096 * 512 * 2);      // m1.k, m2.q
    u16* To    = (u16*)alloc((size_t)4 * 512 * 2048 * 2);      // m0.qvT, m1.qvT, m0.kvT, m2.kvT
    u16* RelT  = (u16*)alloc((size_t)2 * 512 * 4096 * 2);      // m1.kvT, m2.qvT
    // stage-2 buffers
    u16* Pq2   = (u16*)alloc((size_t)2 * 2048 * 3072 * 2);
    u16* Pk2   = (u16*)alloc((size_t)2 * 4096 * 3072 * 2);
    u16* VTa   = (u16*)alloc((size_t)2 * 3072 * 2048 * 2);
    u16* VTs   = (u16*)alloc((size_t)3072 * 2048 * 2);
    u16* Sbuf  = (u16*)alloc((size_t)6 * 4096 * 2048 * 2);     // 96 MiB
    u16* Wt2   = Sbuf;                                          // alias: used before Sbuf writes
    u16* part  = (u16*)alloc((size_t)6 * 4096 * 512 * 2);
    float* rdAll = (float*)alloc((size_t)36864 * 4);
    float* rdQ = rdAll;
    float* rdM = rdAll + 12288;
    float* rs0 = (float*)alloc((size_t)4 * 2048 * 4);
    float* rs1 = (float*)alloc((size_t)4 * 2048 * 4);
    float* rs2 = (float*)alloc((size_t)4 * 4096 * 4);
    float* sub_obj  = (float*)alloc((size_t)2048 * 512 * 4);
    float* obj_sub  = (float*)alloc((size_t)2048 * 512 * 4);
    float* sub_rel  = (float*)alloc((size_t)2048 * 512 * 4);
    float* obj_rel  = (float*)alloc((size_t)2048 * 512 * 4);
    float* rel_obj  = (float*)alloc((size_t)4096 * 512 * 4);
    float* rel_sub  = (float*)alloc((size_t)4096 * 512 * 4);
    float* rel_obj2 = (float*)alloc((size_t)4096 * 512 * 4);
    float* rel_sub2 = (float*)alloc((size_t)4096 * 512 * 4);

    zero_kernel<<<144, 256, 0, stream>>>(rdAll, 36864);
    cvt_bf16_kernel<<<2048, 256, 0, stream>>>((const float4*)feat_obj, (ushort4*)bf_obj, 2048 * 1024 / 4);
    cvt_bf16_kernel<<<4096, 256, 0, stream>>>((const float4*)feat_rel, (ushort4*)bf_rel, 4096 * 1024 / 4);
    transcvt_perm_kernel<<<dim3(16, 32, 12), dim3(32, 8), 0, stream>>>(W_cat, WtP, 1024, 512);
    bias_perm_kernel<<<12, 256, 0, stream>>>(b_cat, rbcat);
    transcvt_kernel<<<dim3(96, 32, 8), dim3(32, 8), 0, stream>>>(W_out, Wt2, 1024, 3072);

    const float sc1 = 0.08838834764831845f;  // 1/sqrt(128)
    const float sc2 = 0.04419417382415922f;  // 1/sqrt(512)
    const long planeW = (long)512 * 1024;
    const long planeW2 = (long)3072 * 1024;
    const long NIL = 0;
    const long pQ = (long)2048 * 512;    // QKo plane (elements)
    const long pRN = (long)4096 * 512;
    const long pT = (long)512 * 2048;
    const long pRT = (long)512 * 4096;

    // ---------------- stage-1 projections: 4 grouped BM=128 dispatches ----------------
    // G0: bf_obj x WtP planes 0..3 -> QKo (normal layout)
    gemm_nt<E_PROJ, 128><<<dim3(16, 4, 4), 256, 0, stream>>>(
        bf_obj, WtP, QKo, nullptr, rbcat, nullptr,
        2048, 512, 1024, 1024, 1024, 512, 0, 0.f, NIL, planeW, pQ, NIL, 512, NIL, 1, NIL, NIL);
    // G1: bf_obj x WtP planes 4..7 -> To (transposed layout, ldcT=2048)
    gemm_nt<E_PROJT, 128><<<dim3(16, 4, 4), 256, 0, stream>>>(
        bf_obj, WtP + 4 * planeW, nullptr, To, rbcat + 4 * 512, nullptr,
        2048, 512, 1024, 1024, 1024, 0, 2048, 0.f, NIL, planeW, NIL, pT, 512, NIL, 1, NIL, NIL);
    // G2: bf_rel x WtP planes 8..9 -> RelN
    gemm_nt<E_PROJ, 128><<<dim3(32, 4, 2), 256, 0, stream>>>(
        bf_rel, WtP + 8 * planeW, RelN, nullptr, rbcat + 8 * 512, nullptr,
        4096, 512, 1024, 1024, 1024, 512, 0, 0.f, NIL, planeW, pRN, NIL, 512, NIL, 1, NIL, NIL);
    // G3: bf_rel x WtP planes 10..11 -> RelT (ldcT=4096)
    gemm_nt<E_PROJT, 128><<<dim3(32, 4, 2), 256, 0, stream>>>(
        bf_rel, WtP + 10 * planeW, nullptr, RelT, rbcat + 10 * 512, nullptr,
        4096, 512, 1024, 1024, 1024, 0, 4096, 0.f, NIL, planeW, NIL, pRT, 512, NIL, 1, NIL, NIL);

    // ---------------- fused stage-1 attention ----------------
    // QKo: [0]=m0.q [1]=m1.q [2]=m0.k [3]=m2.k ; RelN: [0]=m1.k [1]=m2.q
    // To: [0]=m0.qvT [1]=m1.qvT [2]=m0.kvT [3]=m2.kvT ; RelT: [0]=m1.kvT [1]=m2.qvT
    FCfg f1, f2;
    f1.g[0] = { QKo,          QKo + 2 * pQ, To + 2 * pT,  sub_obj, rs0, 2048, 2048, 1 };
    f1.g[1] = { QKo + pQ,     RelN,         RelT,         sub_rel, rs1, 2048, 4096, 0 };
    f1.g[2] = { RelN + pRN,   QKo + 3 * pQ, To + 3 * pT,  rel_obj, rs2, 4096, 2048, 0 };
    fused_attn1_kernel<1><<<dim3(64, 1, 12), 256, 0, stream>>>(f1, sc1);
    // pre-scale pass-2 V buffers by rsinv (per key-column); in-place
    scale_rows_kernel<<<512, 256, 0, stream>>>(To, To, rs0, 2048, 7, 1);
    scale_rows_kernel<<<512, 256, 0, stream>>>(To + pT, To + pT, rs1, 2048, 7, 1);
    scale_rows_kernel<<<1024, 256, 0, stream>>>(RelT + pRT, RelT + pRT, rs2, 4096, 7, 1);
    f2.g[0] = { QKo + 2 * pQ, QKo,          To,           obj_sub, rs0, 2048, 2048, 1 };
    f2.g[1] = { RelN,         QKo + pQ,     To + pT,      rel_sub, rs1, 4096, 2048, 0 };
    f2.g[2] = { QKo + 3 * pQ, RelN + pRN,   RelT + pRT,   obj_rel, rs2, 2048, 4096, 0 };
    fused_attn1_kernel<0><<<dim3(64, 1, 12), 256, 0, stream>>>(f2, sc1);

    combine_obj_kernel<<<2048, 256, 0, stream>>>((const float4*)feat_obj, (const float4*)sub_obj,
        (const float4*)obj_sub, (const float4*)sub_rel, (const float4*)obj_rel,
        (float4*)out_obj, (ushort4*)bf_obj2);
    combine_rel1_kernel<<<4096, 256, 0, stream>>>((const float4*)feat_rel, (const float4*)rel_obj,
        (const float4*)rel_sub, (ushort4*)bf_rel2);

    // ---------------- stage-2 projections (read Wt2 BEFORE Sbuf writes) ----------------
    gemm_nt<E_PROJ, 128><<<dim3(16, 24, 2), 256, 0, stream>>>(
        bf_obj2, Wt2, Pq2, nullptr, b_out, nullptr,
        2048, 3072, 1024, 1024, 1024, 3072, 0, 0.f, NIL, 5 * planeW2, (long)2048 * 3072, NIL,
        5L * 3072, NIL, 1, NIL, NIL);
    gemm_nt<E_PROJ, 128><<<dim3(32, 24, 2), 256, 0, stream>>>(
        bf_rel2, Wt2 + planeW2, Pk2, nullptr, b_out + 3072, nullptr,
        4096, 3072, 1024, 1024, 1024, 3072, 0, 0.f, NIL, 3 * planeW2, (long)4096 * 3072, NIL,
        3L * 3072, NIL, 1, NIL, NIL);
    gemm_nt<E_PROJT, 128><<<dim3(16, 24, 2), 256, 0, stream>>>(
        bf_obj2, Wt2 + 2 * planeW2, nullptr, VTa, b_out + 2 * 3072, nullptr,
        2048, 3072, 1024, 1024, 1024, 0, 2048, 0.f, NIL, 5 * planeW2, NIL, (long)3072 * 2048,
        5L * 3072, NIL, 1, NIL, NIL);

    const long spl2 = (long)4096 * 2048;
    const long vpl2 = (long)4096 * 512;

    // ---------------- stage 2 mha0: a2 only (swapped scores) ----------------
    {
        gemm_nt<E_EXPC, 128><<<dim3(32, 16, 6), 256, 0, stream>>>(
            Pk2, Pq2, Sbuf, nullptr, nullptr, rdQ,
            4096, 2048, 512, 3072, 3072, 2048, 0, sc2, 512, 512, spl2, NIL, NIL, 2048, 1, NIL, NIL);
        scale_rows_kernel<<<3072, 256, 0, stream>>>(VTa, VTs, rdQ, 2048, 9, 0);
        gemm_nt<E_PART, 128><<<dim3(32, 4, 6), 256, 0, stream>>>(
            Sbuf, VTs, part, nullptr, nullptr, nullptr,
            4096, 512, 2048, 2048, 2048, 512, 0, 0.f, spl2, 512L * 2048, vpl2, NIL, NIL, NIL,
            1, NIL, NIL);
        reduce_h_elu_kernel<<<1024, 256, 0, stream>>>(part, rel_sub2, 4096, 6, nullptr);
    }
    // ---------------- stage 2 mha1: a1 only ----------------
    {
        gemm_nt<E_EXP, 128><<<dim3(32, 16, 6), 256, 0, stream>>>(
            Pk2 + (size_t)4096 * 3072, Pq2 + (size_t)2048 * 3072, Sbuf, nullptr, nullptr, rdM,
            4096, 2048, 512, 3072, 3072, 2048, 0, sc2, 512, 512, spl2, NIL, NIL, 4096, 1, NIL, NIL);
        gemm_nt<E_PART, 128><<<dim3(32, 4, 6), 256, 0, stream>>>(
            Sbuf, VTa + (size_t)3072 * 2048, part, nullptr, nullptr, nullptr,
            4096, 512, 2048, 2048, 2048, 512, 0, 0.f, spl2, 512L * 2048, vpl2, NIL, NIL, NIL,
            1, NIL, NIL);
        reduce_h_elu_kernel<<<1024, 256, 0, stream>>>(part, rel_obj2, 4096, 6, rdM);
    }

    combine_rel2_kernel<<<4096, 256, 0, stream>>>((const float4*)feat_rel, (const float4*)rel_obj2,
        (const float4*)rel_sub2, (float4*)out_rel);
}